// Round 6
// baseline (384.291 us; speedup 1.0000x reference)
//
#include <hip/hip_runtime.h>
#include <hip/hip_cooperative_groups.h>

namespace cg = cooperative_groups;

typedef short v8s __attribute__((ext_vector_type(8)));
typedef float f32x4 __attribute__((ext_vector_type(4)));
typedef unsigned short ushort_t;

#define BB    8
#define CIN   512
#define COUT  512
#define SDIM  512

// async global->LDS DMA, 16B per lane (wave-uniform LDS base + lane*16)
#define GLDS(g, l)                                                      \
    __builtin_amdgcn_global_load_lds(                                   \
        (const __attribute__((address_space(1))) void*)(g),             \
        (__attribute__((address_space(3))) void*)(l), 16, 0, 0)

static __device__ __forceinline__ ushort_t f2bf(float f) {
    union { float f; unsigned u; } un; un.f = f;
    unsigned r = un.u + 0x7FFF + ((un.u >> 16) & 1);  // round-to-nearest-even
    return (ushort_t)(r >> 16);
}

// ---------------------------------------------------------------------------
// k_mega: the whole StyleGAN block in ONE cooperative kernel.
// 256 blocks x 512 threads (1 block/CU, co-resident by construction).
// Phase A: wprep (all blocks, 2 (o,c) pairs/thread) + style (blocks 0-7)
// Phase B: xprep (one (b,r) per block) + demod (16 wave-units per block)
// Phase C: gemm (v6 verbatim: 256x256 tile, ring-4 LDS, 1 barrier/K-tile)
// Rationale: prep+overhead has been a ~100-107us invariant across 6 rounds
// while first-principles traffic accounting says the prep work is ~10us.
// Fusing removes all inter-kernel drain/launch serialization; grid syncs
// (cg) order the true dependencies {q,Wb,m} -> {Xt,dmod} -> gemm.
// ---------------------------------------------------------------------------
__global__ __launch_bounds__(512, 2) void k_mega(
    const float* __restrict__ x, const float* __restrict__ style,
    const float* __restrict__ noise, const float* __restrict__ conv_w,
    const float* __restrict__ fc_w, const float* __restrict__ fc_b,
    const float* __restrict__ bias, float* __restrict__ out,
    float* __restrict__ m, float* __restrict__ dmod, float* __restrict__ q,
    float* __restrict__ guard, ushort_t* __restrict__ Xt,
    ushort_t* __restrict__ Wb) {
    __shared__ __align__(16) ushort_t Wt[4][256 * 32];  // gemm ring; aliased in B
    __shared__ __align__(16) ushort_t Xs[4][256 * 32];  // gemm ring; aliased in A

    const int nb = blockIdx.x;   // 0..255
    const int tid = threadIdx.x; // 0..511

    // ======================= phase A: wprep + style ========================
#pragma unroll
    for (int k = 0; k < 2; ++k) {
        const int idx = nb * 1024 + k * 512 + tid;  // covers 512*512 pairs
        const int o = idx >> 9, c = idx & 511;
        float w[3][3];
        const float* wp = conv_w + idx * 9;
        float qs = 0.f;
        for (int i = 0; i < 3; i++)
            for (int j = 0; j < 3; j++) {
                float v = wp[i * 3 + j];
                w[i][j] = v;
                qs += v * v;
            }
        q[idx] = qs;
        const int ch = c >> 5, kg = (c >> 3) & 3, c8 = c & 7;
        for (int py = 0; py < 2; py++) {
            float rs[2][3];
            for (int kx = 0; kx < 3; kx++) {
                rs[0][kx] = (py == 0) ? w[0][kx] : w[0][kx] + w[1][kx];
                rs[1][kx] = (py == 0) ? w[1][kx] + w[2][kx] : w[2][kx];
            }
            for (int px = 0; px < 2; px++) {
                const int p = py * 2 + px;
                float vals[4];
                if (px == 0) {
                    vals[0] = rs[0][0];
                    vals[1] = rs[0][1] + rs[0][2];
                    vals[2] = rs[1][0];
                    vals[3] = rs[1][1] + rs[1][2];
                } else {
                    vals[0] = rs[0][0] + rs[0][1];
                    vals[1] = rs[0][2];
                    vals[2] = rs[1][0] + rs[1][1];
                    vals[3] = rs[1][2];
                }
                for (int t = 0; t < 4; t++)
                    Wb[(size_t)p * (16 * 4 * 4 * 512 * 8) + (size_t)ch * (4 * 4 * 512 * 8)
                       + ((size_t)(t * 4 + kg) * 512 + o) * 8 + c8] = f2bf(vals[t]);
            }
        }
    }
    if (nb < 8) {
        // ---- style role: b = nb, c = tid ----
        float* sst = (float*)&Xs[0][0];
        sst[tid] = style[nb * SDIM + tid];
        __syncthreads();
        float acc = fc_b[tid];
        const float* wr = fc_w + tid * SDIM;
        for (int k2 = 0; k2 < SDIM; k2 += 4) {
            float4 w4 = *(const float4*)(wr + k2);
            acc += w4.x * sst[k2] + w4.y * sst[k2 + 1] + w4.z * sst[k2 + 2] +
                   w4.w * sst[k2 + 3];
        }
        m[nb * CIN + tid] = acc + 1.0f;
    }
    if (nb == 8 && tid < 8) guard[tid] = 0.f;
    __threadfence();
    cg::this_grid().sync();

    // ======================= phase B: xprep + demod ========================
    {
        // ---- xprep role: b = nb>>5, r = nb&31 (c-grouped Xt layout) ----
        ushort_t* lt = &Wt[0][0];  // [q][c], c-stride 528 (33KB <= 64KB)
        const int r = nb & 31, b = nb >> 5;
        for (int s = tid; s < 4096; s += 512) {  // (c, q-quad)
            const int c = s >> 3, q4 = (s & 7) * 4;
            float4 v = *(const float4*)(x + (((size_t)(b * CIN + c) * 32 + r) * 32 + q4));
            const float mv = m[b * CIN + c];
            lt[(q4 + 0) * 528 + c] = f2bf(v.x * mv);
            lt[(q4 + 1) * 528 + c] = f2bf(v.y * mv);
            lt[(q4 + 2) * 528 + c] = f2bf(v.z * mv);
            lt[(q4 + 3) * 528 + c] = f2bf(v.w * mv);
        }
        __syncthreads();
        for (int s = tid; s < 2048; s += 512) {  // (c-group, q)
            const int cg8 = s >> 5, qq = s & 31;
            v8s v = *(v8s*)&lt[qq * 528 + cg8 * 8];
            *(v8s*)(Xt + (((size_t)(b * 64 + cg8) * 1024) + r * 32 + qq) * 8) = v;
        }
    }
#pragma unroll
    for (int rr = 0; rr < 2; ++rr) {
        // ---- demod role: w = nb*16 + rr*8 + wave, one (b,o) per wave ----
        const int w = nb * 16 + rr * 8 + (tid >> 6);
        const int L = tid & 63;
        const int b = w >> 9, o = w & 511;
        float4 q1 = *(const float4*)(q + o * 512 + L * 8);
        float4 q2 = *(const float4*)(q + o * 512 + L * 8 + 4);
        float4 m1 = *(const float4*)(m + b * 512 + L * 8);
        float4 m2 = *(const float4*)(m + b * 512 + L * 8 + 4);
        float acc = m1.x * m1.x * q1.x + m1.y * m1.y * q1.y + m1.z * m1.z * q1.z +
                    m1.w * m1.w * q1.w + m2.x * m2.x * q2.x + m2.y * m2.y * q2.y +
                    m2.z * m2.z * q2.z + m2.w * m2.w * q2.w;
        for (int off = 32; off; off >>= 1) acc += __shfl_down(acc, off, 64);
        if (L == 0) dmod[w] = rsqrtf(acc + 1e-8f);
    }
    __threadfence();
    cg::this_grid().sync();

    // ======================= phase C: gemm (v6 verbatim) ===================
    {
        const int L = tid & 63;

        // bijective chunked XCD swizzle over the 1-D 256-block grid
        const int lin = nb;
        const int log = (lin & 7) * 32 + (lin >> 3);
        const int o0 = (log & 1) * 256;
        const int n0 = ((log >> 1) & 3) * 256;
        const int zz = log >> 3;
        const int b = zz >> 2, p = zz & 3;

        const int wid = tid >> 6;
        const int py = p >> 1, px = p & 1;
        const int ry0 = py ? 0 : -1, cx0 = px ? 0 : -1;
        const int wo = (wid >> 2) * 128, wn = (wid & 3) * 64;
        const int l15 = L & 15, l4 = L >> 4;

        const ushort_t* XtB = Xt + (size_t)b * (64 * 1024 * 8);  // [cg][pix][8]
        const ushort_t* WbP = Wb + (size_t)p * (16 * 4 * 4 * 512 * 8);

        f32x4 acc[8][4];
#pragma unroll
        for (int i = 0; i < 8; i++)
#pragma unroll
            for (int j = 0; j < 4; j++) acc[i][j] = {0.f, 0.f, 0.f, 0.f};

        // LDS slot s (16B units): row = s>>2, stored granule gs = s&3,
        // logical tap = gs ^ ((row>>1)&3). Channels c0..c0+7 (BK=32).
        auto stage1 = [&](int c0, ushort_t* wbuf, ushort_t* xbuf, int i) {
            const int slot = i * 512 + tid;
            const int row = slot >> 2;
            const int tap = (slot & 3) ^ ((row >> 1) & 3);
            const int ldo = (i * 512 + (tid & 448)) * 8;  // wave-uniform base
            const ushort_t* wsrc =
                WbP + (size_t)(c0 >> 5) * (4 * 4 * 512 * 8)
                + ((size_t)((tap * 4 + ((c0 >> 3) & 3)) * 512 + o0 + row)) * 8;
            GLDS(wsrc, wbuf + ldo);
            const int pix = n0 + row;
            const int gr = (pix >> 5) + ry0 + (tap >> 1);
            const int gq = (pix & 31) + cx0 + (tap & 1);
            const ushort_t* xsrc =
                ((unsigned)gr < 32u && (unsigned)gq < 32u)
                    ? XtB + ((size_t)(c0 >> 3) * 1024 + gr * 32 + gq) * 8
                    : (const ushort_t*)guard;
            GLDS(xsrc, xbuf + ldo);
        };

        auto lread = [&](const ushort_t* buf, int row) -> v8s {
            const int gsel = l4 ^ ((row >> 1) & 3);
            return *(const v8s*)&buf[row * 32 + gsel * 8];
        };

        // prologue: stage tiles 0,1,2 (12 ops); wait tile0 (vmcnt(8))
#pragma unroll
        for (int pt = 0; pt < 3; ++pt) {
            stage1(pt * 8, Wt[pt], Xs[pt], 0);
            stage1(pt * 8, Wt[pt], Xs[pt], 1);
        }
        asm volatile("s_waitcnt vmcnt(8)" ::: "memory");
        __builtin_amdgcn_s_barrier();

        for (int t = 0; t < 64; ++t) {
            const ushort_t* wb = Wt[t & 3];
            const ushort_t* xb = Xs[t & 3];
            ushort_t* wnb = Wt[(t + 3) & 3];
            ushort_t* xnb = Xs[(t + 3) & 3];
            const int c0n = (t + 3) * 8;

            v8s af0[4], af1[4], bfr[4];
#pragma unroll
            for (int i = 0; i < 4; i++) af0[i] = lread(wb, wo + i * 16 + l15);
#pragma unroll
            for (int j = 0; j < 4; j++) bfr[j] = lread(xb, wn + j * 16 + l15);
#pragma unroll
            for (int i = 0; i < 4; i++) af1[i] = lread(wb, wo + 64 + i * 16 + l15);

            if (t + 3 < 64) {
                stage1(c0n, wnb, xnb, 0);
                stage1(c0n, wnb, xnb, 1);
            }

            __builtin_amdgcn_s_setprio(1);
#pragma unroll
            for (int i = 0; i < 4; i++)
#pragma unroll
                for (int j = 0; j < 4; j++)
                    acc[i][j] = __builtin_amdgcn_mfma_f32_16x16x32_bf16(
                        af0[i], bfr[j], acc[i][j], 0, 0, 0);
#pragma unroll
            for (int i = 0; i < 4; i++)
#pragma unroll
                for (int j = 0; j < 4; j++)
                    acc[4 + i][j] = __builtin_amdgcn_mfma_f32_16x16x32_bf16(
                        af1[i], bfr[j], acc[4 + i][j], 0, 0, 0);
            __builtin_amdgcn_s_setprio(0);

            if (t <= 61) asm volatile("s_waitcnt vmcnt(4)" ::: "memory");
            else if (t == 62) asm volatile("s_waitcnt vmcnt(0)" ::: "memory");

            __builtin_amdgcn_s_barrier();
        }

        // epilogue: demod * acc + bias + noise, leaky relu
        const float* db = dmod + b * COUT;
        float nz[4];
        int ooff[4];
#pragma unroll
        for (int j = 0; j < 4; j++) {
            const int pix = n0 + wn + j * 16 + l15;
            const int Y = 2 * (pix >> 5) + py, X = 2 * (pix & 31) + px;
            nz[j] = noise[b * 4096 + Y * 64 + X];
            ooff[j] = Y * 64 + X;
        }
        float* outB = out + (size_t)b * COUT * 4096;
#pragma unroll
        for (int i = 0; i < 8; i++) {
            const int ob = o0 + wo + i * 16 + l4 * 4;
            float4 d4 = *(const float4*)(db + ob);
            float4 b4 = *(const float4*)(bias + ob);
            const float dv[4] = {d4.x, d4.y, d4.z, d4.w};
            const float bv[4] = {b4.x, b4.y, b4.z, b4.w};
#pragma unroll
            for (int reg = 0; reg < 4; reg++) {
                float* orow = outB + (size_t)(ob + reg) * 4096;
#pragma unroll
                for (int j = 0; j < 4; j++) {
                    float v = acc[i][j][reg] * dv[reg] + bv[reg] + nz[j];
                    orow[ooff[j]] = v > 0.f ? v : 0.2f * v;
                }
            }
        }
    }
}

// ---------------------------------------------------------------------------
extern "C" void kernel_launch(void* const* d_in, const int* in_sizes, int n_in,
                              void* d_out, int out_size, void* d_ws, size_t ws_size,
                              hipStream_t stream) {
    const float* x      = (const float*)d_in[0];
    const float* style  = (const float*)d_in[1];
    const float* noise  = (const float*)d_in[2];
    const float* conv_w = (const float*)d_in[3];
    const float* fc_w   = (const float*)d_in[4];
    const float* fc_b   = (const float*)d_in[5];
    const float* bias   = (const float*)d_in[6];
    float* out = (float*)d_out;

    float* ws = (float*)d_ws;
    float* m      = ws;             // 8*512 floats
    float* dmod   = ws + 4096;      // 8*512
    float* q      = ws + 8192;      // 512*512
    float* guardp = ws + 270336;    // 8 floats (32B zero guard, 16B-aligned)
    ushort_t* XtU = (ushort_t*)(ws + 270352);  // 8*64*1024*8 bf16 (c-grouped)
    ushort_t* WbU = XtU + 4194304;             // 4*16*4*4*512*8 bf16

    void* kargs[] = {(void*)&x,      (void*)&style, (void*)&noise, (void*)&conv_w,
                     (void*)&fc_w,   (void*)&fc_b,  (void*)&bias,  (void*)&out,
                     (void*)&m,      (void*)&dmod,  (void*)&q,     (void*)&guardp,
                     (void*)&XtU,    (void*)&WbU};
    hipLaunchCooperativeKernel((const void*)k_mega, dim3(256), dim3(512), kargs,
                               0u, stream);
}

// Round 7
// 197.397 us; speedup vs baseline: 1.9468x; 1.9468x over previous
//
#include <hip/hip_runtime.h>

typedef short v8s __attribute__((ext_vector_type(8)));
typedef float f32x4 __attribute__((ext_vector_type(4)));
typedef unsigned short ushort_t;

#define BB    8
#define CIN   512
#define COUT  512
#define SDIM  512

// async global->LDS DMA, 16B per lane (wave-uniform LDS base + lane*16)
#define GLDS(g, l)                                                      \
    __builtin_amdgcn_global_load_lds(                                   \
        (const __attribute__((address_space(1))) void*)(g),             \
        (__attribute__((address_space(3))) void*)(l), 16, 0, 0)

static __device__ __forceinline__ ushort_t f2bf(float f) {
    union { float f; unsigned u; } un; un.f = f;
    unsigned r = un.u + 0x7FFF + ((un.u >> 16) & 1);  // round-to-nearest-even
    return (ushort_t)(r >> 16);
}

// ---------------------------------------------------------------------------
// k_prep1: fused  (role by blockIdx)   [round-5 verbatim]
//   blocks [0,1024):  q[o,c] = sum w^2 ; Wb phase-combined bf16 weights
//   blocks [1024,1040): m[b,c] = 1 + style[b,:] @ fc_w[c,:] + fc_b[c]
//   block 1024 also zeroes the 32B OOB guard used by k_gemm's DMA staging.
// ---------------------------------------------------------------------------
__global__ void k_prep1(const float* __restrict__ style, const float* __restrict__ fc_w,
                        const float* __restrict__ fc_b, float* __restrict__ m,
                        const float* __restrict__ conv_w, float* __restrict__ q,
                        ushort_t* __restrict__ Wb, float* __restrict__ guard) {
    __shared__ float sst[SDIM];
    const int bid = blockIdx.x;
    if (bid < 1024) {
        // ---- wprep role ----
        const int idx = bid * 256 + threadIdx.x;  // o*512 + c
        const int o = idx >> 9, c = idx & 511;
        float w[3][3];
        const float* wp = conv_w + idx * 9;
        float qs = 0.f;
        for (int i = 0; i < 3; i++)
            for (int j = 0; j < 3; j++) {
                float v = wp[i * 3 + j];
                w[i][j] = v;
                qs += v * v;
            }
        q[idx] = qs;
        const int ch = c >> 5, kg = (c >> 3) & 3, c8 = c & 7;
        for (int py = 0; py < 2; py++) {
            float rs[2][3];
            for (int kx = 0; kx < 3; kx++) {
                rs[0][kx] = (py == 0) ? w[0][kx] : w[0][kx] + w[1][kx];
                rs[1][kx] = (py == 0) ? w[1][kx] + w[2][kx] : w[2][kx];
            }
            for (int px = 0; px < 2; px++) {
                const int p = py * 2 + px;
                float vals[4];
                if (px == 0) {
                    vals[0] = rs[0][0];
                    vals[1] = rs[0][1] + rs[0][2];
                    vals[2] = rs[1][0];
                    vals[3] = rs[1][1] + rs[1][2];
                } else {
                    vals[0] = rs[0][0] + rs[0][1];
                    vals[1] = rs[0][2];
                    vals[2] = rs[1][0] + rs[1][1];
                    vals[3] = rs[1][2];
                }
                for (int t = 0; t < 4; t++)
                    Wb[(size_t)p * (16 * 4 * 4 * 512 * 8) + (size_t)ch * (4 * 4 * 512 * 8)
                       + ((size_t)(t * 4 + kg) * 512 + o) * 8 + c8] = f2bf(vals[t]);
            }
        }
    } else {
        // ---- style role ----
        const int sb = bid - 1024;
        const int bx = sb & 1, b = sb >> 1;
        if (sb == 0 && threadIdx.x < 8) guard[threadIdx.x] = 0.f;
        for (int k = threadIdx.x; k < SDIM; k += 256) sst[k] = style[b * SDIM + k];
        __syncthreads();
        const int c = bx * 256 + threadIdx.x;
        float acc = fc_b[c];
        const float* wr = fc_w + c * SDIM;
        for (int k = 0; k < SDIM; k += 4) {
            float4 w4 = *(const float4*)(wr + k);
            acc += w4.x * sst[k] + w4.y * sst[k + 1] + w4.z * sst[k + 2] + w4.w * sst[k + 3];
        }
        m[b * CIN + c] = acc + 1.0f;
    }
}

// ---------------------------------------------------------------------------
// k_prep2: fused  (role by blockIdx)   [round-5 verbatim]
//   blocks [0,256):    Xt[b][c>>3][r*32+q][c&7] = bf16( x[b][c][r][q]*m[b][c] )
//   blocks [256,1280): d[b,o] = rsqrt( sum_c m^2 q + 1e-8 ), one wave/(b,o)
// ---------------------------------------------------------------------------
__global__ void k_prep2(const float* __restrict__ x, const float* __restrict__ m,
                        ushort_t* __restrict__ Xt, const float* __restrict__ q,
                        float* __restrict__ d) {
    __shared__ __align__(16) ushort_t lt[32 * 528];  // [q][c], c-stride 528
    const int bid = blockIdx.x, t = threadIdx.x;
    if (bid < 256) {
        // ---- xprep role ----
        const int r = bid & 31, b = bid >> 5;
        for (int s = t; s < 4096; s += 256) {  // (c, q-quad)
            const int c = s >> 3, q4 = (s & 7) * 4;
            float4 v = *(const float4*)(x + (((size_t)(b * CIN + c) * 32 + r) * 32 + q4));
            const float mv = m[b * CIN + c];
            lt[(q4 + 0) * 528 + c] = f2bf(v.x * mv);
            lt[(q4 + 1) * 528 + c] = f2bf(v.y * mv);
            lt[(q4 + 2) * 528 + c] = f2bf(v.z * mv);
            lt[(q4 + 3) * 528 + c] = f2bf(v.w * mv);
        }
        __syncthreads();
        for (int s = t; s < 2048; s += 256) {  // (c-group, q)
            const int cg = s >> 5, qq = s & 31;
            v8s v = *(v8s*)&lt[qq * 528 + cg * 8];
            *(v8s*)(Xt + (((size_t)(b * 64 + cg) * 1024) + r * 32 + qq) * 8) = v;
        }
    } else {
        // ---- demod role ----
        const int w = (bid - 256) * 4 + (t >> 6);  // 0..4095
        const int L = t & 63;
        const int b = w >> 9, o = w & 511;
        float4 q1 = *(const float4*)(q + o * 512 + L * 8);
        float4 q2 = *(const float4*)(q + o * 512 + L * 8 + 4);
        float4 m1 = *(const float4*)(m + b * 512 + L * 8);
        float4 m2 = *(const float4*)(m + b * 512 + L * 8 + 4);
        float acc = m1.x * m1.x * q1.x + m1.y * m1.y * q1.y + m1.z * m1.z * q1.z +
                    m1.w * m1.w * q1.w + m2.x * m2.x * q2.x + m2.y * m2.y * q2.y +
                    m2.z * m2.z * q2.z + m2.w * m2.w * q2.w;
        for (int off = 32; off; off >>= 1) acc += __shfl_down(acc, off, 64);
        if (L == 0) d[w] = rsqrtf(acc + 1e-8f);
    }
}

// ---------------------------------------------------------------------------
// k_gemm v7: v6 ring-4 single-barrier structure + ONE-TILE-AHEAD register
// prefetch of the 12 fragments. v6's per-tile ledger: 2805 cy measured vs
// 1241 MFMA + ~1400 LDS -> read and MFMA phases barely overlapped (reads(t)
// and MFMA(t) are dependent within a tile). buf[t+1] is barrier-confirmed
// at the end of iter t-1 (vmcnt(4) there confirms tile t+1), so iter t may
// issue ds_reads(t+1) while running MFMA(t): reads serviced UNDER the MFMA
// cluster. Unroll-2 with named A/B fragment sets (static indexing). Ring,
// staging, swizzle, vmcnt taper, epilogue: v6 verbatim (zero conflicts).
// ---------------------------------------------------------------------------
__global__ __launch_bounds__(512, 2) void k_gemm(
    const ushort_t* __restrict__ Xt, const ushort_t* __restrict__ Wb,
    const float* __restrict__ dmod, const float* __restrict__ bias,
    const float* __restrict__ noise, float* __restrict__ out,
    const float* __restrict__ guard) {
    __shared__ __align__(16) ushort_t Wt[4][256 * 32];  // [o-local][k], swizzled
    __shared__ __align__(16) ushort_t Xs[4][256 * 32];  // [n-local][k], swizzled

    const int tid = threadIdx.x;
    const int L = tid & 63;

    // bijective chunked XCD swizzle: 256 blocks, XCD k owns logical [k*32,(k+1)*32)
    const int lin = blockIdx.x + 2 * blockIdx.y + 8 * blockIdx.z;
    const int log = (lin & 7) * 32 + (lin >> 3);
    const int o0 = (log & 1) * 256;
    const int n0 = ((log >> 1) & 3) * 256;
    const int zz = log >> 3;
    const int b = zz >> 2, p = zz & 3;

    const int wid = tid >> 6;
    const int py = p >> 1, px = p & 1;
    const int ry0 = py ? 0 : -1, cx0 = px ? 0 : -1;
    const int wo = (wid >> 2) * 128, wn = (wid & 3) * 64;
    const int l15 = L & 15, l4 = L >> 4;

    const ushort_t* XtB = Xt + (size_t)b * (64 * 1024 * 8);  // [cg][pix][8]
    const ushort_t* WbP = Wb + (size_t)p * (16 * 4 * 4 * 512 * 8);

    f32x4 acc[8][4];
#pragma unroll
    for (int i = 0; i < 8; i++)
#pragma unroll
        for (int j = 0; j < 4; j++) acc[i][j] = {0.f, 0.f, 0.f, 0.f};

    // ---- staging: one op = 512 lanes x 16B = 8KB = half a 16KB tile ----
    // LDS slot s (16B units): row = s>>2, stored granule gs = s&3,
    // logical tap = gs ^ ((row>>1)&3). Channels c0..c0+7 (BK=32).
    auto stage1 = [&](int c0, ushort_t* wbuf, ushort_t* xbuf, int i) {
        const int slot = i * 512 + tid;
        const int row = slot >> 2;
        const int tap = (slot & 3) ^ ((row >> 1) & 3);
        const int ldo = (i * 512 + (tid & 448)) * 8;  // wave-uniform base
        const ushort_t* wsrc =
            WbP + (size_t)(c0 >> 5) * (4 * 4 * 512 * 8)
            + ((size_t)((tap * 4 + ((c0 >> 3) & 3)) * 512 + o0 + row)) * 8;
        GLDS(wsrc, wbuf + ldo);
        const int pix = n0 + row;
        const int gr = (pix >> 5) + ry0 + (tap >> 1);
        const int gq = (pix & 31) + cx0 + (tap & 1);
        const ushort_t* xsrc =
            ((unsigned)gr < 32u && (unsigned)gq < 32u)
                ? XtB + ((size_t)(c0 >> 3) * 1024 + gr * 32 + gq) * 8
                : (const ushort_t*)guard;
        GLDS(xsrc, xbuf + ldo);
    };
    auto stage2 = [&](int t) {  // stage tile t (both halves)
        stage1(t * 8, Wt[t & 3], Xs[t & 3], 0);
        stage1(t * 8, Wt[t & 3], Xs[t & 3], 1);
    };

    // fragment read: row in [0,256), k-granule l4, swizzled
    auto lread = [&](const ushort_t* buf, int row) -> v8s {
        const int gsel = l4 ^ ((row >> 1) & 3);
        return *(const v8s*)&buf[row * 32 + gsel * 8];
    };
    auto readf = [&](int t, v8s* a0, v8s* a1, v8s* bf) {
        const ushort_t* wb2 = Wt[t & 3];
        const ushort_t* xb2 = Xs[t & 3];
#pragma unroll
        for (int i = 0; i < 4; i++) a0[i] = lread(wb2, wo + i * 16 + l15);
#pragma unroll
        for (int j = 0; j < 4; j++) bf[j] = lread(xb2, wn + j * 16 + l15);
#pragma unroll
        for (int i = 0; i < 4; i++) a1[i] = lread(wb2, wo + 64 + i * 16 + l15);
    };
    auto mfma_all = [&](const v8s* a0, const v8s* a1, const v8s* bf) {
        __builtin_amdgcn_s_setprio(1);
#pragma unroll
        for (int i = 0; i < 4; i++)
#pragma unroll
            for (int j = 0; j < 4; j++)
                acc[i][j] = __builtin_amdgcn_mfma_f32_16x16x32_bf16(
                    a0[i], bf[j], acc[i][j], 0, 0, 0);
#pragma unroll
        for (int i = 0; i < 4; i++)
#pragma unroll
            for (int j = 0; j < 4; j++)
                acc[4 + i][j] = __builtin_amdgcn_mfma_f32_16x16x32_bf16(
                    a1[i], bf[j], acc[4 + i][j], 0, 0, 0);
        __builtin_amdgcn_s_setprio(0);
    };

    // ---- prologue: stage tiles 0,1,2; confirm 0,1 (vmcnt(4)); read tile 0 ----
    stage2(0);
    stage2(1);
    stage2(2);
    asm volatile("s_waitcnt vmcnt(4)" ::: "memory");
    __builtin_amdgcn_s_barrier();

    v8s a0A[4], a1A[4], bA[4], a0B[4], a1B[4], bB[4];
    readf(0, a0A, a1A, bA);

    for (int t = 0; t < 64; t += 2) {
        // ---- even slot: compute tile t, prefetch-read tile t+1 ----
        if (t + 3 < 64) stage2(t + 3);
        readf(t + 1, a0B, a1B, bB);  // buf[t+1] confirmed at end of iter t-1
        mfma_all(a0A, a1A, bA);
        if (t <= 60) asm volatile("s_waitcnt vmcnt(4)" ::: "memory");
        __builtin_amdgcn_s_barrier();
        // ---- odd slot: compute tile t+1, prefetch-read tile t+2 ----
        if (t + 4 < 64) stage2(t + 4);
        if (t + 2 < 64) readf(t + 2, a0A, a1A, bA);
        mfma_all(a0B, a1B, bB);
        if (t + 1 <= 60) asm volatile("s_waitcnt vmcnt(4)" ::: "memory");
        else if (t + 1 == 61) asm volatile("s_waitcnt vmcnt(0)" ::: "memory");
        __builtin_amdgcn_s_barrier();
    }

    // ---- epilogue: demod * acc + bias + noise, leaky relu (v3-verified) ----
    const float* db = dmod + b * COUT;
    float nz[4];
    int ooff[4];
#pragma unroll
    for (int j = 0; j < 4; j++) {
        const int pix = n0 + wn + j * 16 + l15;
        const int Y = 2 * (pix >> 5) + py, X = 2 * (pix & 31) + px;
        nz[j] = noise[b * 4096 + Y * 64 + X];
        ooff[j] = Y * 64 + X;
    }
    float* outB = out + (size_t)b * COUT * 4096;
#pragma unroll
    for (int i = 0; i < 8; i++) {
        const int ob = o0 + wo + i * 16 + l4 * 4;
        float4 d4 = *(const float4*)(db + ob);
        float4 b4 = *(const float4*)(bias + ob);
        const float dv[4] = {d4.x, d4.y, d4.z, d4.w};
        const float bv[4] = {b4.x, b4.y, b4.z, b4.w};
#pragma unroll
        for (int reg = 0; reg < 4; reg++) {
            float* orow = outB + (size_t)(ob + reg) * 4096;
#pragma unroll
            for (int j = 0; j < 4; j++) {
                float v = acc[i][j][reg] * dv[reg] + bv[reg] + nz[j];
                orow[ooff[j]] = v > 0.f ? v : 0.2f * v;
            }
        }
    }
}

// ---------------------------------------------------------------------------
extern "C" void kernel_launch(void* const* d_in, const int* in_sizes, int n_in,
                              void* d_out, int out_size, void* d_ws, size_t ws_size,
                              hipStream_t stream) {
    const float* x      = (const float*)d_in[0];
    const float* style  = (const float*)d_in[1];
    const float* noise  = (const float*)d_in[2];
    const float* conv_w = (const float*)d_in[3];
    const float* fc_w   = (const float*)d_in[4];
    const float* fc_b   = (const float*)d_in[5];
    const float* bias   = (const float*)d_in[6];
    float* out = (float*)d_out;

    float* ws = (float*)d_ws;
    float* m     = ws;             // 8*512 floats
    float* dmod  = ws + 4096;      // 8*512
    float* q     = ws + 8192;      // 512*512
    float* guard = ws + 270336;    // 8 floats (32B zero guard, 16B-aligned)
    ushort_t* XtU = (ushort_t*)(ws + 270352);  // 8*64*1024*8 bf16 (c-grouped)
    ushort_t* WbU = XtU + 4194304;             // 4*16*4*4*512*8 bf16

    k_prep1<<<1040, 256, 0, stream>>>(style, fc_w, fc_b, m, conv_w, q, WbU, guard);
    k_prep2<<<1280, 256, 0, stream>>>(x, m, XtU, q, dmod);
    k_gemm<<<dim3(2, 4, 32), 512, 0, stream>>>(XtU, WbU, dmod, bias, noise, out, guard);
}

// Round 8
// 197.133 us; speedup vs baseline: 1.9494x; 1.0013x over previous
//
#include <hip/hip_runtime.h>

typedef short v8s __attribute__((ext_vector_type(8)));
typedef float f32x4 __attribute__((ext_vector_type(4)));
typedef unsigned short ushort_t;

#define BB    8
#define CIN   512
#define COUT  512
#define SDIM  512

// async global->LDS DMA, 16B per lane (wave-uniform LDS base + lane*16)
#define GLDS(g, l)                                                      \
    __builtin_amdgcn_global_load_lds(                                   \
        (const __attribute__((address_space(1))) void*)(g),             \
        (__attribute__((address_space(3))) void*)(l), 16, 0, 0)

static __device__ __forceinline__ ushort_t f2bf(float f) {
    union { float f; unsigned u; } un; un.f = f;
    unsigned r = un.u + 0x7FFF + ((un.u >> 16) & 1);  // round-to-nearest-even
    return (ushort_t)(r >> 16);
}

// ---------------------------------------------------------------------------
// k_prep1: fused  (role by blockIdx)   [round-5 verbatim]
//   blocks [0,1024):  q[o,c] = sum w^2 ; Wb phase-combined bf16 weights
//   blocks [1024,1040): m[b,c] = 1 + style[b,:] @ fc_w[c,:] + fc_b[c]
//   block 1024 also zeroes the 32B OOB guard used by k_gemm's DMA staging.
// ---------------------------------------------------------------------------
__global__ void k_prep1(const float* __restrict__ style, const float* __restrict__ fc_w,
                        const float* __restrict__ fc_b, float* __restrict__ m,
                        const float* __restrict__ conv_w, float* __restrict__ q,
                        ushort_t* __restrict__ Wb, float* __restrict__ guard) {
    __shared__ float sst[SDIM];
    const int bid = blockIdx.x;
    if (bid < 1024) {
        // ---- wprep role ----
        const int idx = bid * 256 + threadIdx.x;  // o*512 + c
        const int o = idx >> 9, c = idx & 511;
        float w[3][3];
        const float* wp = conv_w + idx * 9;
        float qs = 0.f;
        for (int i = 0; i < 3; i++)
            for (int j = 0; j < 3; j++) {
                float v = wp[i * 3 + j];
                w[i][j] = v;
                qs += v * v;
            }
        q[idx] = qs;
        const int ch = c >> 5, kg = (c >> 3) & 3, c8 = c & 7;
        for (int py = 0; py < 2; py++) {
            float rs[2][3];
            for (int kx = 0; kx < 3; kx++) {
                rs[0][kx] = (py == 0) ? w[0][kx] : w[0][kx] + w[1][kx];
                rs[1][kx] = (py == 0) ? w[1][kx] + w[2][kx] : w[2][kx];
            }
            for (int px = 0; px < 2; px++) {
                const int p = py * 2 + px;
                float vals[4];
                if (px == 0) {
                    vals[0] = rs[0][0];
                    vals[1] = rs[0][1] + rs[0][2];
                    vals[2] = rs[1][0];
                    vals[3] = rs[1][1] + rs[1][2];
                } else {
                    vals[0] = rs[0][0] + rs[0][1];
                    vals[1] = rs[0][2];
                    vals[2] = rs[1][0] + rs[1][1];
                    vals[3] = rs[1][2];
                }
                for (int t = 0; t < 4; t++)
                    Wb[(size_t)p * (16 * 4 * 4 * 512 * 8) + (size_t)ch * (4 * 4 * 512 * 8)
                       + ((size_t)(t * 4 + kg) * 512 + o) * 8 + c8] = f2bf(vals[t]);
            }
        }
    } else {
        // ---- style role ----
        const int sb = bid - 1024;
        const int bx = sb & 1, b = sb >> 1;
        if (sb == 0 && threadIdx.x < 8) guard[threadIdx.x] = 0.f;
        for (int k = threadIdx.x; k < SDIM; k += 256) sst[k] = style[b * SDIM + k];
        __syncthreads();
        const int c = bx * 256 + threadIdx.x;
        float acc = fc_b[c];
        const float* wr = fc_w + c * SDIM;
        for (int k = 0; k < SDIM; k += 4) {
            float4 w4 = *(const float4*)(wr + k);
            acc += w4.x * sst[k] + w4.y * sst[k + 1] + w4.z * sst[k + 2] + w4.w * sst[k + 3];
        }
        m[b * CIN + c] = acc + 1.0f;
    }
}

// ---------------------------------------------------------------------------
// k_prep2: fused  (role by blockIdx)   [round-5 verbatim]
//   blocks [0,256):    Xt[b][c>>3][r*32+q][c&7] = bf16( x[b][c][r][q]*m[b][c] )
//   blocks [256,1280): d[b,o] = rsqrt( sum_c m^2 q + 1e-8 ), one wave/(b,o)
// ---------------------------------------------------------------------------
__global__ void k_prep2(const float* __restrict__ x, const float* __restrict__ m,
                        ushort_t* __restrict__ Xt, const float* __restrict__ q,
                        float* __restrict__ d) {
    __shared__ __align__(16) ushort_t lt[32 * 528];  // [q][c], c-stride 528
    const int bid = blockIdx.x, t = threadIdx.x;
    if (bid < 256) {
        // ---- xprep role ----
        const int r = bid & 31, b = bid >> 5;
        for (int s = t; s < 4096; s += 256) {  // (c, q-quad)
            const int c = s >> 3, q4 = (s & 7) * 4;
            float4 v = *(const float4*)(x + (((size_t)(b * CIN + c) * 32 + r) * 32 + q4));
            const float mv = m[b * CIN + c];
            lt[(q4 + 0) * 528 + c] = f2bf(v.x * mv);
            lt[(q4 + 1) * 528 + c] = f2bf(v.y * mv);
            lt[(q4 + 2) * 528 + c] = f2bf(v.z * mv);
            lt[(q4 + 3) * 528 + c] = f2bf(v.w * mv);
        }
        __syncthreads();
        for (int s = t; s < 2048; s += 256) {  // (c-group, q)
            const int cg = s >> 5, qq = s & 31;
            v8s v = *(v8s*)&lt[qq * 528 + cg * 8];
            *(v8s*)(Xt + (((size_t)(b * 64 + cg) * 1024) + r * 32 + qq) * 8) = v;
        }
    } else {
        // ---- demod role ----
        const int w = (bid - 256) * 4 + (t >> 6);  // 0..4095
        const int L = t & 63;
        const int b = w >> 9, o = w & 511;
        float4 q1 = *(const float4*)(q + o * 512 + L * 8);
        float4 q2 = *(const float4*)(q + o * 512 + L * 8 + 4);
        float4 m1 = *(const float4*)(m + b * 512 + L * 8);
        float4 m2 = *(const float4*)(m + b * 512 + L * 8 + 4);
        float acc = m1.x * m1.x * q1.x + m1.y * m1.y * q1.y + m1.z * m1.z * q1.z +
                    m1.w * m1.w * q1.w + m2.x * m2.x * q2.x + m2.y * m2.y * q2.y +
                    m2.z * m2.z * q2.z + m2.w * m2.w * q2.w;
        for (int off = 32; off; off >>= 1) acc += __shfl_down(acc, off, 64);
        if (L == 0) d[w] = rsqrtf(acc + 1e-8f);
    }
}

// ---------------------------------------------------------------------------
// k_gemm v8: v7's one-tile-ahead register prefetch + sched_barrier(0) pin.
// v7 regressed (93us, MfmaUtil 28.9) because the scheduler SANK the
// readf(t+1) ds_reads below the MFMA cluster (minimizing the 96-VGPR live
// range) -> same serial LDS/MFMA alternation as v6 but with more pressure.
// One sched_barrier(0) between readf(t+1) and mfma_all(t) pins the intended
// order: reads issue first, LDS services them UNDER the MFMA cluster, and
// the lgkm waits for them land before the NEXT slot's MFMAs. Everything
// else (ring-4, staging, swizzle, vmcnt taper, epilogue) v7/v6 verbatim.
// ---------------------------------------------------------------------------
__global__ __launch_bounds__(512, 2) void k_gemm(
    const ushort_t* __restrict__ Xt, const ushort_t* __restrict__ Wb,
    const float* __restrict__ dmod, const float* __restrict__ bias,
    const float* __restrict__ noise, float* __restrict__ out,
    const float* __restrict__ guard) {
    __shared__ __align__(16) ushort_t Wt[4][256 * 32];  // [o-local][k], swizzled
    __shared__ __align__(16) ushort_t Xs[4][256 * 32];  // [n-local][k], swizzled

    const int tid = threadIdx.x;
    const int L = tid & 63;

    // bijective chunked XCD swizzle: 256 blocks, XCD k owns logical [k*32,(k+1)*32)
    const int lin = blockIdx.x + 2 * blockIdx.y + 8 * blockIdx.z;
    const int log = (lin & 7) * 32 + (lin >> 3);
    const int o0 = (log & 1) * 256;
    const int n0 = ((log >> 1) & 3) * 256;
    const int zz = log >> 3;
    const int b = zz >> 2, p = zz & 3;

    const int wid = tid >> 6;
    const int py = p >> 1, px = p & 1;
    const int ry0 = py ? 0 : -1, cx0 = px ? 0 : -1;
    const int wo = (wid >> 2) * 128, wn = (wid & 3) * 64;
    const int l15 = L & 15, l4 = L >> 4;

    const ushort_t* XtB = Xt + (size_t)b * (64 * 1024 * 8);  // [cg][pix][8]
    const ushort_t* WbP = Wb + (size_t)p * (16 * 4 * 4 * 512 * 8);

    f32x4 acc[8][4];
#pragma unroll
    for (int i = 0; i < 8; i++)
#pragma unroll
        for (int j = 0; j < 4; j++) acc[i][j] = {0.f, 0.f, 0.f, 0.f};

    // ---- staging: one op = 512 lanes x 16B = 8KB = half a 16KB tile ----
    // LDS slot s (16B units): row = s>>2, stored granule gs = s&3,
    // logical tap = gs ^ ((row>>1)&3). Channels c0..c0+7 (BK=32).
    auto stage1 = [&](int c0, ushort_t* wbuf, ushort_t* xbuf, int i) {
        const int slot = i * 512 + tid;
        const int row = slot >> 2;
        const int tap = (slot & 3) ^ ((row >> 1) & 3);
        const int ldo = (i * 512 + (tid & 448)) * 8;  // wave-uniform base
        const ushort_t* wsrc =
            WbP + (size_t)(c0 >> 5) * (4 * 4 * 512 * 8)
            + ((size_t)((tap * 4 + ((c0 >> 3) & 3)) * 512 + o0 + row)) * 8;
        GLDS(wsrc, wbuf + ldo);
        const int pix = n0 + row;
        const int gr = (pix >> 5) + ry0 + (tap >> 1);
        const int gq = (pix & 31) + cx0 + (tap & 1);
        const ushort_t* xsrc =
            ((unsigned)gr < 32u && (unsigned)gq < 32u)
                ? XtB + ((size_t)(c0 >> 3) * 1024 + gr * 32 + gq) * 8
                : (const ushort_t*)guard;
        GLDS(xsrc, xbuf + ldo);
    };
    auto stage2 = [&](int t) {  // stage tile t (both halves)
        stage1(t * 8, Wt[t & 3], Xs[t & 3], 0);
        stage1(t * 8, Wt[t & 3], Xs[t & 3], 1);
    };

    // fragment read: row in [0,256), k-granule l4, swizzled
    auto lread = [&](const ushort_t* buf, int row) -> v8s {
        const int gsel = l4 ^ ((row >> 1) & 3);
        return *(const v8s*)&buf[row * 32 + gsel * 8];
    };
    auto readf = [&](int t, v8s* a0, v8s* a1, v8s* bf) {
        const ushort_t* wb2 = Wt[t & 3];
        const ushort_t* xb2 = Xs[t & 3];
#pragma unroll
        for (int i = 0; i < 4; i++) a0[i] = lread(wb2, wo + i * 16 + l15);
#pragma unroll
        for (int j = 0; j < 4; j++) bf[j] = lread(xb2, wn + j * 16 + l15);
#pragma unroll
        for (int i = 0; i < 4; i++) a1[i] = lread(wb2, wo + 64 + i * 16 + l15);
    };
    auto mfma_all = [&](const v8s* a0, const v8s* a1, const v8s* bf) {
        __builtin_amdgcn_s_setprio(1);
#pragma unroll
        for (int i = 0; i < 4; i++)
#pragma unroll
            for (int j = 0; j < 4; j++)
                acc[i][j] = __builtin_amdgcn_mfma_f32_16x16x32_bf16(
                    a0[i], bf[j], acc[i][j], 0, 0, 0);
#pragma unroll
        for (int i = 0; i < 4; i++)
#pragma unroll
            for (int j = 0; j < 4; j++)
                acc[4 + i][j] = __builtin_amdgcn_mfma_f32_16x16x32_bf16(
                    a1[i], bf[j], acc[4 + i][j], 0, 0, 0);
        __builtin_amdgcn_s_setprio(0);
    };

    // ---- prologue: stage tiles 0,1,2; confirm 0,1 (vmcnt(4)); read tile 0 ----
    stage2(0);
    stage2(1);
    stage2(2);
    asm volatile("s_waitcnt vmcnt(4)" ::: "memory");
    __builtin_amdgcn_s_barrier();

    v8s a0A[4], a1A[4], bA[4], a0B[4], a1B[4], bB[4];
    readf(0, a0A, a1A, bA);

    for (int t = 0; t < 64; t += 2) {
        // ---- even slot: compute tile t, prefetch-read tile t+1 ----
        if (t + 3 < 64) stage2(t + 3);
        readf(t + 1, a0B, a1B, bB);  // buf[t+1] confirmed at end of iter t-1
        __builtin_amdgcn_sched_barrier(0);  // PIN: reads issue BEFORE the MFMA
        mfma_all(a0A, a1A, bA);             //      cluster; LDS services them
        if (t <= 60) asm volatile("s_waitcnt vmcnt(4)" ::: "memory");
        __builtin_amdgcn_s_barrier();
        // ---- odd slot: compute tile t+1, prefetch-read tile t+2 ----
        if (t + 4 < 64) stage2(t + 4);
        if (t + 2 < 64) readf(t + 2, a0A, a1A, bA);
        __builtin_amdgcn_sched_barrier(0);
        mfma_all(a0B, a1B, bB);
        if (t + 1 <= 60) asm volatile("s_waitcnt vmcnt(4)" ::: "memory");
        else if (t + 1 == 61) asm volatile("s_waitcnt vmcnt(0)" ::: "memory");
        __builtin_amdgcn_s_barrier();
    }

    // ---- epilogue: demod * acc + bias + noise, leaky relu (v3-verified) ----
    const float* db = dmod + b * COUT;
    float nz[4];
    int ooff[4];
#pragma unroll
    for (int j = 0; j < 4; j++) {
        const int pix = n0 + wn + j * 16 + l15;
        const int Y = 2 * (pix >> 5) + py, X = 2 * (pix & 31) + px;
        nz[j] = noise[b * 4096 + Y * 64 + X];
        ooff[j] = Y * 64 + X;
    }
    float* outB = out + (size_t)b * COUT * 4096;
#pragma unroll
    for (int i = 0; i < 8; i++) {
        const int ob = o0 + wo + i * 16 + l4 * 4;
        float4 d4 = *(const float4*)(db + ob);
        float4 b4 = *(const float4*)(bias + ob);
        const float dv[4] = {d4.x, d4.y, d4.z, d4.w};
        const float bv[4] = {b4.x, b4.y, b4.z, b4.w};
#pragma unroll
        for (int reg = 0; reg < 4; reg++) {
            float* orow = outB + (size_t)(ob + reg) * 4096;
#pragma unroll
            for (int j = 0; j < 4; j++) {
                float v = acc[i][j][reg] * dv[reg] + bv[reg] + nz[j];
                orow[ooff[j]] = v > 0.f ? v : 0.2f * v;
            }
        }
    }
}

// ---------------------------------------------------------------------------
extern "C" void kernel_launch(void* const* d_in, const int* in_sizes, int n_in,
                              void* d_out, int out_size, void* d_ws, size_t ws_size,
                              hipStream_t stream) {
    const float* x      = (const float*)d_in[0];
    const float* style  = (const float*)d_in[1];
    const float* noise  = (const float*)d_in[2];
    const float* conv_w = (const float*)d_in[3];
    const float* fc_w   = (const float*)d_in[4];
    const float* fc_b   = (const float*)d_in[5];
    const float* bias   = (const float*)d_in[6];
    float* out = (float*)d_out;

    float* ws = (float*)d_ws;
    float* m     = ws;             // 8*512 floats
    float* dmod  = ws + 4096;      // 8*512
    float* q     = ws + 8192;      // 512*512
    float* guard = ws + 270336;    // 8 floats (32B zero guard, 16B-aligned)
    ushort_t* XtU = (ushort_t*)(ws + 270352);  // 8*64*1024*8 bf16 (c-grouped)
    ushort_t* WbU = XtU + 4194304;             // 4*16*4*4*512*8 bf16

    k_prep1<<<1040, 256, 0, stream>>>(style, fc_w, fc_b, m, conv_w, q, WbU, guard);
    k_prep2<<<1280, 256, 0, stream>>>(x, m, XtU, q, dmod);
    k_gemm<<<dim3(2, 4, 32), 512, 0, stream>>>(XtU, WbU, dmod, bias, noise, out, guard);
}

// Round 9
// 189.385 us; speedup vs baseline: 2.0291x; 1.0409x over previous
//
#include <hip/hip_runtime.h>

typedef short v8s __attribute__((ext_vector_type(8)));
typedef float f32x4 __attribute__((ext_vector_type(4)));
typedef unsigned short ushort_t;

#define BB    8
#define CIN   512
#define COUT  512
#define SDIM  512

// async global->LDS DMA, 16B per lane (wave-uniform LDS base + lane*16)
#define GLDS(g, l)                                                      \
    __builtin_amdgcn_global_load_lds(                                   \
        (const __attribute__((address_space(1))) void*)(g),             \
        (__attribute__((address_space(3))) void*)(l), 16, 0, 0)

static __device__ __forceinline__ ushort_t f2bf(float f) {
    union { float f; unsigned u; } un; un.f = f;
    unsigned r = un.u + 0x7FFF + ((un.u >> 16) & 1);  // round-to-nearest-even
    return (ushort_t)(r >> 16);
}

// ---------------------------------------------------------------------------
// k_prep1: fused  (role by blockIdx)   [round-5 verbatim]
// ---------------------------------------------------------------------------
__global__ void k_prep1(const float* __restrict__ style, const float* __restrict__ fc_w,
                        const float* __restrict__ fc_b, float* __restrict__ m,
                        const float* __restrict__ conv_w, float* __restrict__ q,
                        ushort_t* __restrict__ Wb, float* __restrict__ guard) {
    __shared__ float sst[SDIM];
    const int bid = blockIdx.x;
    if (bid < 1024) {
        // ---- wprep role ----
        const int idx = bid * 256 + threadIdx.x;  // o*512 + c
        const int o = idx >> 9, c = idx & 511;
        float w[3][3];
        const float* wp = conv_w + idx * 9;
        float qs = 0.f;
        for (int i = 0; i < 3; i++)
            for (int j = 0; j < 3; j++) {
                float v = wp[i * 3 + j];
                w[i][j] = v;
                qs += v * v;
            }
        q[idx] = qs;
        const int ch = c >> 5, kg = (c >> 3) & 3, c8 = c & 7;
        for (int py = 0; py < 2; py++) {
            float rs[2][3];
            for (int kx = 0; kx < 3; kx++) {
                rs[0][kx] = (py == 0) ? w[0][kx] : w[0][kx] + w[1][kx];
                rs[1][kx] = (py == 0) ? w[1][kx] + w[2][kx] : w[2][kx];
            }
            for (int px = 0; px < 2; px++) {
                const int p = py * 2 + px;
                float vals[4];
                if (px == 0) {
                    vals[0] = rs[0][0];
                    vals[1] = rs[0][1] + rs[0][2];
                    vals[2] = rs[1][0];
                    vals[3] = rs[1][1] + rs[1][2];
                } else {
                    vals[0] = rs[0][0] + rs[0][1];
                    vals[1] = rs[0][2];
                    vals[2] = rs[1][0] + rs[1][1];
                    vals[3] = rs[1][2];
                }
                for (int t = 0; t < 4; t++)
                    Wb[(size_t)p * (16 * 4 * 4 * 512 * 8) + (size_t)ch * (4 * 4 * 512 * 8)
                       + ((size_t)(t * 4 + kg) * 512 + o) * 8 + c8] = f2bf(vals[t]);
            }
        }
    } else {
        // ---- style role ----
        const int sb = bid - 1024;
        const int bx = sb & 1, b = sb >> 1;
        if (sb == 0 && threadIdx.x < 8) guard[threadIdx.x] = 0.f;
        for (int k = threadIdx.x; k < SDIM; k += 256) sst[k] = style[b * SDIM + k];
        __syncthreads();
        const int c = bx * 256 + threadIdx.x;
        float acc = fc_b[c];
        const float* wr = fc_w + c * SDIM;
        for (int k = 0; k < SDIM; k += 4) {
            float4 w4 = *(const float4*)(wr + k);
            acc += w4.x * sst[k] + w4.y * sst[k + 1] + w4.z * sst[k + 2] + w4.w * sst[k + 3];
        }
        m[b * CIN + c] = acc + 1.0f;
    }
}

// ---------------------------------------------------------------------------
// k_prep2: fused  (role by blockIdx)   [round-5 verbatim]
// ---------------------------------------------------------------------------
__global__ void k_prep2(const float* __restrict__ x, const float* __restrict__ m,
                        ushort_t* __restrict__ Xt, const float* __restrict__ q,
                        float* __restrict__ d) {
    __shared__ __align__(16) ushort_t lt[32 * 528];  // [q][c], c-stride 528
    const int bid = blockIdx.x, t = threadIdx.x;
    if (bid < 256) {
        // ---- xprep role ----
        const int r = bid & 31, b = bid >> 5;
        for (int s = t; s < 4096; s += 256) {  // (c, q-quad)
            const int c = s >> 3, q4 = (s & 7) * 4;
            float4 v = *(const float4*)(x + (((size_t)(b * CIN + c) * 32 + r) * 32 + q4));
            const float mv = m[b * CIN + c];
            lt[(q4 + 0) * 528 + c] = f2bf(v.x * mv);
            lt[(q4 + 1) * 528 + c] = f2bf(v.y * mv);
            lt[(q4 + 2) * 528 + c] = f2bf(v.z * mv);
            lt[(q4 + 3) * 528 + c] = f2bf(v.w * mv);
        }
        __syncthreads();
        for (int s = t; s < 2048; s += 256) {  // (c-group, q)
            const int cg = s >> 5, qq = s & 31;
            v8s v = *(v8s*)&lt[qq * 528 + cg * 8];
            *(v8s*)(Xt + (((size_t)(b * 64 + cg) * 1024) + r * 32 + qq) * 8) = v;
        }
    } else {
        // ---- demod role ----
        const int w = (bid - 256) * 4 + (t >> 6);  // 0..4095
        const int L = t & 63;
        const int b = w >> 9, o = w & 511;
        float4 q1 = *(const float4*)(q + o * 512 + L * 8);
        float4 q2 = *(const float4*)(q + o * 512 + L * 8 + 4);
        float4 m1 = *(const float4*)(m + b * 512 + L * 8);
        float4 m2 = *(const float4*)(m + b * 512 + L * 8 + 4);
        float acc = m1.x * m1.x * q1.x + m1.y * m1.y * q1.y + m1.z * m1.z * q1.z +
                    m1.w * m1.w * q1.w + m2.x * m2.x * q2.x + m2.y * m2.y * q2.y +
                    m2.z * m2.z * q2.z + m2.w * m2.w * q2.w;
        for (int off = 32; off; off >>= 1) acc += __shfl_down(acc, off, 64);
        if (L == 0) d[w] = rsqrtf(acc + 1e-8f);
    }
}

// ---------------------------------------------------------------------------
// k_gemm v9: v6's schedule at 2 BLOCKS/CU. v6 (1 block/CU) is fully serial
// per tile: all 8 waves barrier-aligned -> CU alternates {LDS busy, matrix
// idle}/{matrix busy, LDS idle} (2805 cy ~ 1150 reads + 1241 MFMA + sync).
// Intra-block staggering failed 3x (v5, v7, v8). The PROVEN overlap source
// (m97/m114: implicit cross-block interleave at >=2 blocks/CU) was lost
// when LDS grew to 128KB. Restore it: block tile 256pix x 128o (wave 64x64,
// acc[4][4]), BK=32, ring-3 LDS = 3 x (8KB W + 16KB X) = 72KB -> exactly
// 2 blocks/CU; grid 512 = 2/CU. Everything else v6-verbatim: 1 barrier per
// tile, stage t+2 (3 GLDS/thread), counted vmcnt(3) (0 only at t=62), same
// swizzle + read pattern (measured zero conflicts), same epilogue math.
// ---------------------------------------------------------------------------
__global__ __launch_bounds__(512, 4) void k_gemm(
    const ushort_t* __restrict__ Xt, const ushort_t* __restrict__ Wb,
    const float* __restrict__ dmod, const float* __restrict__ bias,
    const float* __restrict__ noise, float* __restrict__ out,
    const float* __restrict__ guard) {
    __shared__ __align__(16) ushort_t Wt[3][128 * 32];  // [o-local][k], swizzled
    __shared__ __align__(16) ushort_t Xs[3][256 * 32];  // [n-local][k], swizzled

    const int tid = threadIdx.x;
    const int L = tid & 63;

    // bijective chunked XCD swizzle: 512 blocks, XCD k owns logical [k*64,(k+1)*64)
    const int lin = blockIdx.x + 4 * blockIdx.y + 16 * blockIdx.z;
    const int log = (lin & 7) * 64 + (lin >> 3);
    const int o0 = (log & 3) * 128;
    const int n0 = ((log >> 2) & 3) * 256;
    const int zz = log >> 4;
    const int b = zz >> 2, p = zz & 3;

    const int wid = tid >> 6;
    const int py = p >> 1, px = p & 1;
    const int ry0 = py ? 0 : -1, cx0 = px ? 0 : -1;
    const int wo = (wid & 1) * 64, wn = (wid >> 1) * 64;
    const int l15 = L & 15, l4 = L >> 4;

    const ushort_t* XtB = Xt + (size_t)b * (64 * 1024 * 8);  // [cg][pix][8]
    const ushort_t* WbP = Wb + (size_t)p * (16 * 4 * 4 * 512 * 8);

    f32x4 acc[4][4];
#pragma unroll
    for (int i = 0; i < 4; i++)
#pragma unroll
        for (int j = 0; j < 4; j++) acc[i][j] = {0.f, 0.f, 0.f, 0.f};

    // ---- staging (v6-verbatim index math, resized panels) ----
    // W-tile 128 rows = 8KB = 1 op/thread; X-tile 256 rows = 16KB = 2 ops.
    // LDS slot s (16B units): row = s>>2, stored granule gs = s&3,
    // logical tap = gs ^ ((row>>1)&3). Channels c0..c0+7 (BK=32).
    auto stage_w = [&](int c0, ushort_t* wbuf) {
        const int row = tid >> 2;  // 0..127
        const int tap = (tid & 3) ^ ((row >> 1) & 3);
        const ushort_t* wsrc =
            WbP + (size_t)(c0 >> 5) * (4 * 4 * 512 * 8)
            + ((size_t)((tap * 4 + ((c0 >> 3) & 3)) * 512 + o0 + row)) * 8;
        GLDS(wsrc, wbuf + (size_t)(tid & 448) * 8);
    };
    auto stage_x = [&](int c0, ushort_t* xbuf) {
#pragma unroll
        for (int i = 0; i < 2; i++) {
            const int slot = i * 512 + tid;
            const int row = slot >> 2;  // 0..255
            const int tap = (slot & 3) ^ ((row >> 1) & 3);
            const int pix = n0 + row;
            const int gr = (pix >> 5) + ry0 + (tap >> 1);
            const int gq = (pix & 31) + cx0 + (tap & 1);
            const ushort_t* xsrc =
                ((unsigned)gr < 32u && (unsigned)gq < 32u)
                    ? XtB + ((size_t)(c0 >> 3) * 1024 + gr * 32 + gq) * 8
                    : (const ushort_t*)guard;
            GLDS(xsrc, xbuf + (size_t)(i * 512 + (tid & 448)) * 8);
        }
    };

    // fragment read: k-granule l4, swizzled (zero-conflict pattern, v6)
    auto lread = [&](const ushort_t* buf, int row) -> v8s {
        const int gsel = l4 ^ ((row >> 1) & 3);
        return *(const v8s*)&buf[row * 32 + gsel * 8];
    };

    // ---- prologue: stage tiles 0,1 (6 ops); wait tile0 (vmcnt(3)) ----
    stage_w(0, Wt[0]);
    stage_x(0, Xs[0]);
    stage_w(8, Wt[1]);
    stage_x(8, Xs[1]);
    asm volatile("s_waitcnt vmcnt(3)" ::: "memory");
    __builtin_amdgcn_s_barrier();

    int cur = 0;
    for (int t = 0; t < 64; ++t) {
        const ushort_t* wt = Wt[cur];
        const ushort_t* xs = Xs[cur];
        const int stg = (cur == 0) ? 2 : cur - 1;  // (cur+2)%3

        // 1. issue this tile's 8 fragment reads (compiler-counted lgkm waits)
        v8s af[4], bfr[4];
#pragma unroll
        for (int i = 0; i < 4; i++) af[i] = lread(wt, wo + i * 16 + l15);
#pragma unroll
        for (int j = 0; j < 4; j++) bfr[j] = lread(xs, wn + j * 16 + l15);

        // 2. stage tile t+2 into the ring (its buffer's reads consumed at t-1)
        if (t + 2 < 64) {
            stage_w((t + 2) * 8, Wt[stg]);
            stage_x((t + 2) * 8, Xs[stg]);
        }

        // 3. MFMA: 16 per wave
        __builtin_amdgcn_s_setprio(1);
#pragma unroll
        for (int i = 0; i < 4; i++)
#pragma unroll
            for (int j = 0; j < 4; j++)
                acc[i][j] = __builtin_amdgcn_mfma_f32_16x16x32_bf16(
                    af[i], bfr[j], acc[i][j], 0, 0, 0);
        __builtin_amdgcn_s_setprio(0);

        // 4. counted vmcnt BEFORE the barrier: confirm tile t+1 staged
        //    (leave t+2's 3 ops in flight); drain only at the tail
        if (t <= 61) asm volatile("s_waitcnt vmcnt(3)" ::: "memory");
        else if (t == 62) asm volatile("s_waitcnt vmcnt(0)" ::: "memory");

        // 5. single block-wide rendezvous per K-tile
        __builtin_amdgcn_s_barrier();
        cur = (cur == 2) ? 0 : cur + 1;
    }

    // ---- epilogue: demod * acc + bias + noise, leaky relu (v6-verbatim) ----
    const float* db = dmod + b * COUT;
    float nz[4];
    int ooff[4];
#pragma unroll
    for (int j = 0; j < 4; j++) {
        const int pix = n0 + wn + j * 16 + l15;
        const int Y = 2 * (pix >> 5) + py, X = 2 * (pix & 31) + px;
        nz[j] = noise[b * 4096 + Y * 64 + X];
        ooff[j] = Y * 64 + X;
    }
    float* outB = out + (size_t)b * COUT * 4096;
#pragma unroll
    for (int i = 0; i < 4; i++) {
        const int ob = o0 + wo + i * 16 + l4 * 4;
        float4 d4 = *(const float4*)(db + ob);
        float4 b4 = *(const float4*)(bias + ob);
        const float dv[4] = {d4.x, d4.y, d4.z, d4.w};
        const float bv[4] = {b4.x, b4.y, b4.z, b4.w};
#pragma unroll
        for (int reg = 0; reg < 4; reg++) {
            float* orow = outB + (size_t)(ob + reg) * 4096;
#pragma unroll
            for (int j = 0; j < 4; j++) {
                float v = acc[i][j][reg] * dv[reg] + bv[reg] + nz[j];
                orow[ooff[j]] = v > 0.f ? v : 0.2f * v;
            }
        }
    }
}

// ---------------------------------------------------------------------------
extern "C" void kernel_launch(void* const* d_in, const int* in_sizes, int n_in,
                              void* d_out, int out_size, void* d_ws, size_t ws_size,
                              hipStream_t stream) {
    const float* x      = (const float*)d_in[0];
    const float* style  = (const float*)d_in[1];
    const float* noise  = (const float*)d_in[2];
    const float* conv_w = (const float*)d_in[3];
    const float* fc_w   = (const float*)d_in[4];
    const float* fc_b   = (const float*)d_in[5];
    const float* bias   = (const float*)d_in[6];
    float* out = (float*)d_out;

    float* ws = (float*)d_ws;
    float* m     = ws;             // 8*512 floats
    float* dmod  = ws + 4096;      // 8*512
    float* q     = ws + 8192;      // 512*512
    float* guard = ws + 270336;    // 8 floats (32B zero guard, 16B-aligned)
    ushort_t* XtU = (ushort_t*)(ws + 270352);  // 8*64*1024*8 bf16 (c-grouped)
    ushort_t* WbU = XtU + 4194304;             // 4*16*4*4*512*8 bf16

    k_prep1<<<1040, 256, 0, stream>>>(style, fc_w, fc_b, m, conv_w, q, WbU, guard);
    k_prep2<<<1280, 256, 0, stream>>>(x, m, XtU, q, dmod);
    k_gemm<<<dim3(4, 4, 32), 512, 0, stream>>>(XtU, WbU, dmod, bias, noise, out, guard);
}